// Round 7
// baseline (731.417 us; speedup 1.0000x reference)
//
#include <hip/hip_runtime.h>
#include <cmath>

// FISTA sparse coding, bf16-MFMA (round 11 = round-10 resubmit; container flake).
// Round-9 = 718 us (ring-3 counted vmcnt). This round:
//   D-GEMMs (K=512, Nn=2048) move to gemm_bt256: BM=256 x BN=128, 8 waves,
//   __launch_bounds__(512,4) -> 2 blocks/CU (16 waves/CU, 4/SIMD vs 3),
//   128 MFMA per barrier (vs 64), ring-3 LDS (72KB) + counted vmcnt(3),
//   T1 swizzle, same rolling epilogue prefetch. Per-output accumulation
//   order unchanged -> bit-identical c, absmax 0.03125.
//   C-GEMMs (Nn=512) stay on the verified 128x128 ring-3 kernel.

typedef __attribute__((ext_vector_type(8))) short bf16x8;          // 4 VGPRs
typedef __attribute__((ext_vector_type(8))) unsigned short u16x8;  // 16 B
typedef __attribute__((ext_vector_type(4))) float f32x4;

constexpr float S_STEP = 0.1f;   // step size
constexpr float LAM    = 0.01f;  // lmbd * step (mu=0 -> s_mu=1)

__device__ __forceinline__ unsigned short f2bf(float f) {   // RNE fp32->bf16
    unsigned u = __float_as_uint(f);
    u += 0x7FFFu + ((u >> 16) & 1u);
    return (unsigned short)(u >> 16);
}
__device__ __forceinline__ float bf2f(unsigned short s) {
    return __uint_as_float(((unsigned)s) << 16);
}

__device__ __forceinline__ void async16(const void* g, void* l) {
    __builtin_amdgcn_global_load_lds(
        (const __attribute__((address_space(1))) void*)g,
        (__attribute__((address_space(3))) void*)l, 16, 0, 0);
}

// ===========================================================================
// gemm_bt256<EPI>: D-output GEMMs. BM=256, BN=128, BK=32, K=512, Nn=2048.
//   EPI 0: OutB = bf16(relu(S*acc - LAM))                          (c0)
//   EPI 1: OutB = bf16(relu(cfA*Cc + cfB*Cpre + S*acc - LAM))      (c1..c3)
//   EPI 2: EPI1 + Out32 = w fp32 + closs += 0.1*sum(w)             (c4)
// 512 thr = 8 waves (4 row-groups x 2 col-groups), per-wave 64x64, acc[4][4].
// LDS 73728B: ring slot s at s*24576B: A 16KB (256x32), B 8KB (128x32).
// Grid flat 1024 (64 by x 16 bx), T1 XCD swizzle.
// ===========================================================================
template<int EPI>
__global__ __launch_bounds__(512, 4)
void gemm_bt256(const short* __restrict__ A, const short* __restrict__ B,
                const unsigned short* __restrict__ Cc,
                const unsigned short* __restrict__ Cpre,
                unsigned short* __restrict__ OutB, float* __restrict__ Out32,
                float cfA, float cfB, float* __restrict__ loss)
{
    constexpr int K = 512, Nn = 2048, NT = 16;
    __shared__ __align__(16) unsigned char smem[73728];
    short* S  = (short*)smem;                 // slot s: +s*12288 shorts
    float (*L)[132] = (float (*)[132])smem;   // epilogue bounce 32x132 fp32
    float* red2 = (float*)(smem + 73696);     // 8 floats

    const int tid  = threadIdx.x;
    const int wave = tid >> 6;
    const int lane = tid & 63;
    const int wr   = wave >> 1;      // 0..3 row-group (64 rows)
    const int wc   = wave & 1;       // 0..1 col-group (64 cols)
    const int m16  = lane & 15;
    const int quad = lane >> 4;

    // T1 bijective XCD swizzle: 1024 blocks, 128/XCD contiguous
    const int idx = (blockIdx.x & 7) * 128 + (blockIdx.x >> 3);
    const int rowBase = (idx >> 4) * 256;     // by 0..63
    const int colBase = (idx & 15) * 128;     // bx 0..15

    // staging: per iter, wave stages A rows [w*32,w*32+32) (2 loads) and
    // B rows [w*16,w*16+16) (1 load); lane -> row l>>2, k-chunk (l&3)*8
    const int sRow = lane >> 2;
    const int sK   = (lane & 3) << 3;
    const short* gA0 = A + (size_t)(rowBase + wave * 32 + sRow) * K + sK;
    const short* gB0 = B + (size_t)(colBase + wave * 16 + sRow) * K + sK;
    const size_t rstep16 = (size_t)16 * K;
    short* lA = S + wave * 1024;              // + slot*12288
    short* lB = S + 8192 + wave * 512;        // + slot*12288

    const short* paBase = S + (wr * 64 + m16) * 32 + quad * 8;         // + slot*12288
    const short* pbBase = S + 8192 + (wc * 64 + m16) * 32 + quad * 8;  // + slot*12288

    f32x4 acc[4][4] = {};

    // ---- ring-3 prologue: stage tiles 0,1 (3 loads each); wait tile 0 ----
    {
        async16(gA0,           lA);
        async16(gA0 + rstep16, lA + 512);
        async16(gB0,           lB);
        async16(gA0 + 32,           lA + 12288);
        async16(gA0 + 32 + rstep16, lA + 12288 + 512);
        async16(gB0 + 32,           lB + 12288);
        asm volatile("s_waitcnt vmcnt(3)" ::: "memory");
        __builtin_amdgcn_s_barrier();
    }

    int sSt = 2, sRd = 0;
    for (int it = 0; it < NT; ++it) {
        if (it + 2 < NT) {
            const int kb = (it + 2) << 5;
            short* sA = lA + sSt * 12288;
            short* sB = lB + sSt * 12288;
            async16(gA0 + kb,           sA);
            async16(gA0 + kb + rstep16, sA + 512);
            async16(gB0 + kb,           sB);
        }
        const int cb = sRd * 12288;
        bf16x8 af[4], bfr[4];
        #pragma unroll
        for (int i = 0; i < 4; ++i) af[i]  = *(const bf16x8*)(paBase + cb + i * 512);
        #pragma unroll
        for (int j = 0; j < 4; ++j) bfr[j] = *(const bf16x8*)(pbBase + cb + j * 512);
        #pragma unroll
        for (int i = 0; i < 4; ++i)
            #pragma unroll
            for (int j = 0; j < 4; ++j)
                acc[i][j] = __builtin_amdgcn_mfma_f32_16x16x32_bf16(
                                af[i], bfr[j], acc[i][j], 0, 0, 0);
        if (it + 2 < NT)      asm volatile("s_waitcnt vmcnt(3)" ::: "memory");
        else if (it + 1 < NT) asm volatile("s_waitcnt vmcnt(0)" ::: "memory");
        if (it + 1 < NT) __builtin_amdgcn_s_barrier();
        sSt = (sSt == 2) ? 0 : sSt + 1;
        sRd = (sRd == 2) ? 0 : sRd + 1;
    }

    // ---- epilogue: 8 chunks of 32 rows, [32][132] bounce, rolling prefetch --
    // acc row = wr*64 + i*16 + quad*4 + r; col = wc*64 + j*16 + m16
    const int lrow = tid >> 4;        // 0..31
    const int seg  = tid & 15;        // 8-col segment
    const bool useCp = (cfB != 0.f);
    float lsum = 0.f;

    auto gofs = [&](int t) -> size_t {
        return (size_t)(rowBase + t * 32 + lrow) * Nn + colBase + seg * 8;
    };

    u16x8 cc{}, cp{};
    if constexpr (EPI == 1 || EPI == 2) {
        const size_t g = gofs(0);
        cc = *(const u16x8*)(Cc + g);
        if (useCp) cp = *(const u16x8*)(Cpre + g);
    }

    #pragma unroll
    for (int t = 0; t < 8; ++t) {
        __syncthreads();
        if (wr == (t >> 1)) {
            #pragma unroll
            for (int ii = 0; ii < 2; ++ii) {
                const int i   = (t & 1) * 2 + ii;
                const int lr0 = ii * 16 + quad * 4;
                #pragma unroll
                for (int r = 0; r < 4; ++r)
                    #pragma unroll
                    for (int j = 0; j < 4; ++j)
                        L[lr0 + r][wc * 64 + j * 16 + m16] = acc[i][j][r];
            }
        }
        __syncthreads();

        float v[8];
        *(f32x4*)&v[0] = *(const f32x4*)&L[lrow][seg * 8];
        *(f32x4*)&v[4] = *(const f32x4*)&L[lrow][seg * 8 + 4];

        const size_t gidx = gofs(t);

        u16x8 ncc{}, ncp{};
        if (t < 7) {
            if constexpr (EPI == 1 || EPI == 2) {
                const size_t gn = gofs(t + 1);
                ncc = *(const u16x8*)(Cc + gn);
                if (useCp) ncp = *(const u16x8*)(Cpre + gn);
            }
        }

        if constexpr (EPI == 0) {
            u16x8 o;
            #pragma unroll
            for (int k = 0; k < 8; ++k)
                o[k] = f2bf(fmaxf(S_STEP * v[k] - LAM, 0.f));
            *(u16x8*)(OutB + gidx) = o;
        } else {
            float w[8];
            u16x8 o;
            #pragma unroll
            for (int k = 0; k < 8; ++k) {
                w[k] = fmaxf(cfA * bf2f(cc[k]) + cfB * bf2f(cp[k])
                             + S_STEP * v[k] - LAM, 0.f);
                o[k] = f2bf(w[k]);
            }
            *(u16x8*)(OutB + gidx) = o;
            if constexpr (EPI == 2) {
                *(f32x4*)(Out32 + gidx)     = *(const f32x4*)&w[0];
                *(f32x4*)(Out32 + gidx + 4) = *(const f32x4*)&w[4];
                #pragma unroll
                for (int k = 0; k < 8; ++k) lsum += w[k];   // w >= 0
            }
        }

        if (t < 7) {
            if constexpr (EPI == 1 || EPI == 2) {
                cc = ncc;
                if (useCp) cp = ncp;
            }
        }
    }

    if constexpr (EPI == 2) {
        #pragma unroll
        for (int off = 32; off; off >>= 1) lsum += __shfl_down(lsum, off, 64);
        if (lane == 0) red2[wave] = lsum;
        __syncthreads();
        if (tid == 0) {
            float s = 0.f;
            #pragma unroll
            for (int wv = 0; wv < 8; ++wv) s += red2[wv];
            atomicAdd(loss, 0.1f * s);
        }
    }
}

// ===========================================================================
// gemm_bt<EPI>: 128x128 ring-3 kernel — C-output GEMMs.
//   EPI 3: OutB = bf16(Xb - acc)   (r intermediate, bf16 x read)
//   EPI 4: Out32 = acc (xp), R32 = Xf - acc (r), loss += sum(r*r)  (fused)
// ===========================================================================
template<int EPI>
__global__ __launch_bounds__(256)
void gemm_bt(const short* __restrict__ A, const short* __restrict__ B,
             int K, int Nn, int lbx,
             const unsigned short* __restrict__ Xb, const float* __restrict__ Xf,
             unsigned short* __restrict__ OutB, float* Out32, float* R32,
             float* loss)
{
    __shared__ __align__(16) unsigned char smem[49152];
    short* S  = (short*)smem;
    float (*L)[132] = (float (*)[132])smem;
    float* red2 = (float*)(smem + 49088);

    const int tid  = threadIdx.x;
    const int wave = tid >> 6;
    const int lane = tid & 63;

    const int qchunk = gridDim.x >> 3;
    const int idx    = (blockIdx.x & 7) * qchunk + (blockIdx.x >> 3);
    const int rowBase = (idx >> lbx) * 128;
    const int colBase = (idx & ((1 << lbx) - 1)) * 128;

    const int sRow = lane >> 2;
    const int sK   = (lane & 3) << 3;
    const short* gA = A + (size_t)(rowBase + wave * 32 + sRow) * K + sK;
    const short* gB = B + (size_t)(colBase + wave * 32 + sRow) * K + sK;
    const size_t rstep = (size_t)16 * K;
    short* lA = S + wave * 1024;
    short* lB = S + 4096 + wave * 1024;

    const int m16  = lane & 15;
    const int quad = lane >> 4;
    const short* paBase = S + ((wave & 1) * 64 + m16) * 32 + quad * 8;
    const short* pbBase = S + 4096 + ((wave >> 1) * 64 + m16) * 32 + quad * 8;

    f32x4 acc[4][4] = {};
    const int nIter = K >> 5;

    {
        async16(gA,         lA);
        async16(gA + rstep, lA + 512);
        async16(gB,         lB);
        async16(gB + rstep, lB + 512);
        async16(gA + 32,         lA + 8192);
        async16(gA + 32 + rstep, lA + 8192 + 512);
        async16(gB + 32,         lB + 8192);
        async16(gB + 32 + rstep, lB + 8192 + 512);
        asm volatile("s_waitcnt vmcnt(4)" ::: "memory");
        __builtin_amdgcn_s_barrier();
    }

    int sSt = 2, sRd = 0;
    for (int it = 0; it < nIter; ++it) {
        if (it + 2 < nIter) {
            const int kb = (it + 2) << 5;
            short* sA = lA + sSt * 8192;
            short* sB = lB + sSt * 8192;
            async16(gA + kb,         sA);
            async16(gA + kb + rstep, sA + 512);
            async16(gB + kb,         sB);
            async16(gB + kb + rstep, sB + 512);
        }
        const int cb = sRd * 8192;
        bf16x8 af[4], bfr[4];
        #pragma unroll
        for (int i = 0; i < 4; ++i) af[i]  = *(const bf16x8*)(paBase + cb + i * 512);
        #pragma unroll
        for (int j = 0; j < 4; ++j) bfr[j] = *(const bf16x8*)(pbBase + cb + j * 512);
        #pragma unroll
        for (int i = 0; i < 4; ++i)
            #pragma unroll
            for (int j = 0; j < 4; ++j)
                acc[i][j] = __builtin_amdgcn_mfma_f32_16x16x32_bf16(
                                af[i], bfr[j], acc[i][j], 0, 0, 0);
        if (it + 2 < nIter)      asm volatile("s_waitcnt vmcnt(4)" ::: "memory");
        else if (it + 1 < nIter) asm volatile("s_waitcnt vmcnt(0)" ::: "memory");
        if (it + 1 < nIter) __builtin_amdgcn_s_barrier();
        sSt = (sSt == 2) ? 0 : sSt + 1;
        sRd = (sRd == 2) ? 0 : sRd + 1;
    }

    const int lrow = tid >> 3;
    const int seg  = tid & 7;
    float lsum = 0.f;

    auto gofs = [&](int t) -> size_t {
        return (size_t)(rowBase + t * 32 + lrow) * Nn + colBase + seg * 16;
    };

    u16x8 xq0{}, xq1{};
    float xfv[16];
    if constexpr (EPI == 3) {
        const size_t g = gofs(0);
        xq0 = *(const u16x8*)(Xb + g); xq1 = *(const u16x8*)(Xb + g + 8);
    } else if constexpr (EPI == 4) {
        const size_t g = gofs(0);
        #pragma unroll
        for (int q = 0; q < 4; ++q)
            *(f32x4*)&xfv[q * 4] = *(const f32x4*)(Xf + g + q * 4);
    }

    #pragma unroll
    for (int t = 0; t < 4; ++t) {
        __syncthreads();
        if ((wave & 1) == (t >> 1)) {
            #pragma unroll
            for (int ii = 0; ii < 2; ++ii) {
                const int i   = (t & 1) * 2 + ii;
                const int lr0 = ii * 16 + quad * 4;
                #pragma unroll
                for (int r = 0; r < 4; ++r)
                    #pragma unroll
                    for (int j = 0; j < 4; ++j)
                        L[lr0 + r][(wave >> 1) * 64 + j * 16 + m16] = acc[i][j][r];
            }
        }
        __syncthreads();

        float v[16];
        #pragma unroll
        for (int q = 0; q < 4; ++q)
            *(f32x4*)&v[q * 4] = *(const f32x4*)&L[lrow][seg * 16 + q * 4];

        const size_t gidx = gofs(t);

        u16x8 nxq0{}, nxq1{};
        float nxfv[16];
        if (t < 3) {
            const size_t gn = gofs(t + 1);
            if constexpr (EPI == 3) {
                nxq0 = *(const u16x8*)(Xb + gn); nxq1 = *(const u16x8*)(Xb + gn + 8);
            } else if constexpr (EPI == 4) {
                #pragma unroll
                for (int q = 0; q < 4; ++q)
                    *(f32x4*)&nxfv[q * 4] = *(const f32x4*)(Xf + gn + q * 4);
            }
        }

        if constexpr (EPI == 3) {
            u16x8 o0, o1;
            #pragma unroll
            for (int k = 0; k < 8; ++k) {
                o0[k] = f2bf(bf2f(xq0[k]) - v[k]);
                o1[k] = f2bf(bf2f(xq1[k]) - v[k + 8]);
            }
            *(u16x8*)(OutB + gidx)     = o0;
            *(u16x8*)(OutB + gidx + 8) = o1;
        } else {  // EPI 4
            float rv[16];
            #pragma unroll
            for (int k = 0; k < 16; ++k) {
                rv[k] = xfv[k] - v[k];
                lsum += rv[k] * rv[k];
            }
            #pragma unroll
            for (int q = 0; q < 4; ++q) {
                *(f32x4*)(Out32 + gidx + q * 4) = *(const f32x4*)&v[q * 4];
                *(f32x4*)(R32   + gidx + q * 4) = *(const f32x4*)&rv[q * 4];
            }
        }

        if (t < 3) {
            if constexpr (EPI == 3) {
                xq0 = nxq0; xq1 = nxq1;
            } else if constexpr (EPI == 4) {
                #pragma unroll
                for (int k = 0; k < 16; ++k) xfv[k] = nxfv[k];
            }
        }
    }

    if constexpr (EPI == 4) {
        #pragma unroll
        for (int off = 32; off; off >>= 1) lsum += __shfl_down(lsum, off, 64);
        if (lane == 0) red2[wave] = lsum;
        __syncthreads();
        if (tid == 0)
            atomicAdd(loss, red2[0] + red2[1] + red2[2] + red2[3]);
    }
}

// ---------------------------------------------------------------------------
// prep: W [2048,512] fp32 -> Wb bf16 (same layout) + Wtb bf16 [512,2048]
// ---------------------------------------------------------------------------
__global__ __launch_bounds__(256)
void cvt_w_k(const float* __restrict__ W,
             unsigned short* __restrict__ Wb, unsigned short* __restrict__ Wtb)
{
    __shared__ unsigned short T[64][65];
    const int dBase = blockIdx.y * 64;
    const int cBase = blockIdx.x * 64;
    const int lc = threadIdx.x & 63;
    const int lr = threadIdx.x >> 6;
    #pragma unroll
    for (int p = 0; p < 16; ++p) {
        const int dl = p * 4 + lr;
        const size_t idx = (size_t)(dBase + dl) * 512 + cBase + lc;
        const unsigned short b = f2bf(W[idx]);
        Wb[idx] = b;
        T[dl][lc] = b;
    }
    __syncthreads();
    #pragma unroll
    for (int p = 0; p < 16; ++p) {
        const int cl = p * 4 + lr;
        Wtb[(size_t)(cBase + cl) * 2048 + dBase + lc] = T[lc][cl];
    }
}

__global__ __launch_bounds__(256)
void cvt_x_k(const float4* __restrict__ x4, ushort4* __restrict__ xb4, int n4)
{
    for (int i = blockIdx.x * 256 + threadIdx.x; i < n4; i += gridDim.x * 256) {
        const float4 v = x4[i];
        xb4[i] = make_ushort4(f2bf(v.x), f2bf(v.y), f2bf(v.z), f2bf(v.w));
    }
}

// 2MB Wtb -> cb1 copy (cb1 dead after step-4 EPI2)
__global__ __launch_bounds__(256)
void copy_wtb_k(const u16x8* __restrict__ src, u16x8* __restrict__ dst)
{
    const int i = blockIdx.x * 256 + threadIdx.x;
    dst[i] = src[i];
}

// ---------------------------------------------------------------------------
extern "C" void kernel_launch(void* const* d_in, const int* in_sizes, int n_in,
                              void* d_out, int out_size, void* d_ws, size_t ws_size,
                              hipStream_t stream)
{
    (void)in_sizes; (void)n_in; (void)out_size; (void)ws_size;

    constexpr int N = 16384, C = 512, D = 2048;
    constexpr size_t ND = (size_t)N * D;
    constexpr size_t NC = (size_t)N * C;

    const float* x = (const float*)d_in[0];   // [N, C]
    const float* W = (const float*)d_in[1];   // [D, C]

    float* out    = (float*)d_out;
    float* c_out  = out;                      // c  [N, D] fp32
    float* xp_out = out + ND;                 // xp [N, C] fp32
    float* r_out  = out + ND + NC;            // r  [N, C] fp32
    float* rloss  = out + ND + 2 * NC;
    float* closs  = rloss + 1;

    // ws: two bf16 c generations (64 MiB each)
    short* cb0 = (short*)d_ws;
    short* cb1 = cb0 + ND;

    // scratch in dead phases of d_out:
    unsigned short* rb  = (unsigned short*)xp_out;            // [N,C] bf16
    unsigned short* Wb  = (unsigned short*)xp_out + NC;       // [D,C] bf16
    unsigned short* Wtb = (unsigned short*)r_out;             // [C,D] bf16
    unsigned short* xb  = (unsigned short*)r_out + (size_t)D * C;  // [N,C] bf16

    hipMemsetAsync((void*)rloss, 0, 2 * sizeof(float), stream);

    double tp = (std::sqrt(5.0) + 1.0) / 2.0;
    float cfA[5] = {0.f, 1.f, 0.f, 0.f, 0.f};
    float cfB[5] = {0.f, 0.f, 0.f, 0.f, 0.f};
    for (int i = 2; i < 5; ++i) {
        double t = (std::sqrt(1.0 + 4.0 * tp * tp) + 1.0) / 2.0;
        cfA[i] = (float)((tp + t - 1.0) / t);
        cfB[i] = (float)((1.0 - tp) / t);
        tp = t;
    }

    const dim3 blk(256);
    const dim3 blk512(512);
    cvt_w_k<<<dim3(C / 64, D / 64), blk, 0, stream>>>(W, Wb, Wtb);
    cvt_x_k<<<dim3(1024), blk, 0, stream>>>((const float4*)x, (ushort4*)xb,
                                            (int)(NC / 4));

    const dim3 gridD((N / 256) * (D / 128));   // 1024 blocks (64 by x 16 bx)
    const dim3 gridC((C / 128) * (N / 128));   //  512 blocks, lbx=2
    constexpr int LBX_C = 2;

    // c0 = relu(S*(x@W^T) - LAM)
    gemm_bt256<0><<<gridD, blk512, 0, stream>>>(
        (const short*)xb, (const short*)Wb, nullptr, nullptr,
        (unsigned short*)cb0, nullptr, 0.f, 0.f, nullptr);

    short* bufs[2] = {cb0, cb1};
    for (int i = 1; i < 5; ++i) {
        const short* cprev = bufs[(i - 1) & 1];   // c_{i-1}
        short*       cnew  = bufs[i & 1];         // c_{i-2} -> c_i (in place)
        const unsigned short* cpre2 =
            (i == 1) ? (const unsigned short*)cprev : (const unsigned short*)cnew;
        // r_{i-1} = x - c_{i-1} @ W   (bf16, via Wt; reads xb)
        gemm_bt<3><<<gridC, blk, 0, stream>>>(cprev, (const short*)Wtb,
                                              D, C, LBX_C,
                                              xb, nullptr,
                                              rb, nullptr, nullptr, nullptr);
        // c_i = relu(cfA*c_{i-1} + cfB*c_{i-2} + S*(r@W^T) - LAM)
        if (i < 4)
            gemm_bt256<1><<<gridD, blk512, 0, stream>>>(
                (const short*)rb, (const short*)Wb,
                (const unsigned short*)cprev, cpre2,
                (unsigned short*)cnew, nullptr, cfA[i], cfB[i], nullptr);
        else
            gemm_bt256<2><<<gridD, blk512, 0, stream>>>(
                (const short*)rb, (const short*)Wb,
                (const unsigned short*)cprev, cpre2,
                (unsigned short*)cnew, c_out, cfA[i], cfB[i], closs);
    }

    // Wtb -> cb1 (cb1 dead after step-4 EPI2); EPI4 writes r over original Wtb
    copy_wtb_k<<<dim3(512), blk, 0, stream>>>((const u16x8*)Wtb, (u16x8*)cb1);

    // xp = c4 @ W (fp32), r = x - xp, rloss  — fused (overwrites rb/Wb/Wtb/xb)
    gemm_bt<4><<<gridC, blk, 0, stream>>>(cb0, (const short*)cb1,
                                          D, C, LBX_C,
                                          nullptr, x,
                                          nullptr, xp_out, r_out, rloss);
}

// Round 8
// 714.942 us; speedup vs baseline: 1.0230x; 1.0230x over previous
//
#include <hip/hip_runtime.h>
#include <cmath>

// FISTA sparse coding, bf16-MFMA (round 12).
// Revert D-GEMMs to 128x128 ring-3 (round-9 = 718 us; BM=256 regressed).
// New this round, on the unified 128x128 kernel:
//   (1) T2 XOR k-chunk swizzle (rule 21): global SOURCE pre-swizzled
//       (kc ^= (lane>>3)&3), LDS linear, ds_read applies same involution
//       (quad ^= (m16>>1)&3). Turns the 8-way bank conflict of the
//       m16*64B-stride read into a free 2-way. Bit-identical MFMA inputs.
//   (2) __launch_bounds__(256,4): VGPR <= 128 -> 16 waves/CU (4 blocks).
// EPI2 closs back to 4-wave reduction -> absmax expected exactly 0.03125.

typedef __attribute__((ext_vector_type(8))) short bf16x8;          // 4 VGPRs
typedef __attribute__((ext_vector_type(8))) unsigned short u16x8;  // 16 B
typedef __attribute__((ext_vector_type(4))) float f32x4;

constexpr float S_STEP = 0.1f;   // step size
constexpr float LAM    = 0.01f;  // lmbd * step (mu=0 -> s_mu=1)

__device__ __forceinline__ unsigned short f2bf(float f) {   // RNE fp32->bf16
    unsigned u = __float_as_uint(f);
    u += 0x7FFFu + ((u >> 16) & 1u);
    return (unsigned short)(u >> 16);
}
__device__ __forceinline__ float bf2f(unsigned short s) {
    return __uint_as_float(((unsigned)s) << 16);
}

__device__ __forceinline__ void async16(const void* g, void* l) {
    __builtin_amdgcn_global_load_lds(
        (const __attribute__((address_space(1))) void*)g,
        (__attribute__((address_space(3))) void*)l, 16, 0, 0);
}

// ---------------------------------------------------------------------------
// gemm_bt<EPI>: acc[m,n] = sum_k A[m,k]*B[n,k]; A:[M,K] bf16 rm, B:[Nn,K] bf16 rm.
//   EPI 0: OutB = bf16(relu(S*acc - LAM))                          (c0)
//   EPI 1: OutB = bf16(relu(cfA*Cc + cfB*Cpre + S*acc - LAM))      (c1..c3)
//   EPI 2: EPI1 + Out32 = w (fp32 c) + closs += 0.1*sum(w)         (c4)
//   EPI 3: OutB = bf16(Xb - acc)   (r intermediate, bf16 x read)
//   EPI 4: Out32 = acc (xp), R32 = Xf - acc (r), loss += sum(r*r)  (fused)
// Grid is FLAT; lbx = log2(Nn/128). T1: XCD k owns a contiguous by-range.
// LDS 49152B: ring slot s (s=0..2) at s*16384B: A 8KB then B 8KB.
// T2: LDS phys chunk p of row r holds logical k-chunk p ^ ((r>>1)&3);
//     source addr carries the XOR, reads apply the same XOR. LDS linear.
// ---------------------------------------------------------------------------
template<int EPI>
__global__ __launch_bounds__(256, 4)
void gemm_bt(const short* __restrict__ A, const short* __restrict__ B,
             int K, int Nn, int lbx,
             const unsigned short* Cc, const unsigned short* Cpre,
             const unsigned short* __restrict__ Xb, const float* __restrict__ Xf,
             unsigned short* OutB, float* Out32, float* R32,
             float cfA, float cfB, float* loss)
{
    __shared__ __align__(16) unsigned char smem[49152];
    short* S  = (short*)smem;                 // ring slots (shorts): s*8192
    float (*L)[132] = (float (*)[132])smem;   // epilogue bounce, first 16896 B
    float* red2 = (float*)(smem + 49088);     // 4 floats, after bounce region

    const int tid  = threadIdx.x;
    const int wave = tid >> 6;
    const int lane = tid & 63;

    // T1: bijective XCD swizzle (gridDim.x % 8 == 0 for both 2048 and 512)
    const int qchunk = gridDim.x >> 3;
    const int idx    = (blockIdx.x & 7) * qchunk + (blockIdx.x >> 3);
    const int rowBase = (idx >> lbx) * 128;
    const int colBase = (idx & ((1 << lbx) - 1)) * 128;

    // staging map: 16 rows x 32 k per instr; lane L -> row L/4,
    // T2 source swizzle: k-chunk = (L%4) ^ ((L>>3)&3), *8 elements
    const int sRow = lane >> 2;
    const int sK   = (((lane & 3) ^ ((lane >> 3) & 3)) << 3);
    const short* gA = A + (size_t)(rowBase + wave * 32 + sRow) * K + sK;
    const short* gB = B + (size_t)(colBase + wave * 32 + sRow) * K + sK;
    const size_t rstep = (size_t)16 * K;
    short* lA = S + wave * 1024;              // + slot*8192 (shorts)
    short* lB = S + 4096 + wave * 1024;       // + slot*8192

    const int m16  = lane & 15;
    const int quad = lane >> 4;
    // T2 read swizzle: phys chunk = quad ^ ((row>>1)&3); (row>>1)&3 == (m16>>1)&3
    const int ksw  = (m16 >> 1) & 3;
    const short* paBase = S + ((wave & 1) * 64 + m16) * 32 + (quad ^ ksw) * 8;
    const short* pbBase = S + 4096 + ((wave >> 1) * 64 + m16) * 32 + (quad ^ ksw) * 8;

    f32x4 acc[4][4] = {};
    const int nIter = K >> 5;

    // ---- ring-3 prologue: stage tiles 0,1; wait tile 0 (4 own loads) ----
    {
        async16(gA,         lA);
        async16(gA + rstep, lA + 512);
        async16(gB,         lB);
        async16(gB + rstep, lB + 512);
        async16(gA + 32,         lA + 8192);
        async16(gA + 32 + rstep, lA + 8192 + 512);
        async16(gB + 32,         lB + 8192);
        async16(gB + 32 + rstep, lB + 8192 + 512);
        asm volatile("s_waitcnt vmcnt(4)" ::: "memory");
        __builtin_amdgcn_s_barrier();
    }

    int sSt = 2;   // slot receiving tile it+2
    int sRd = 0;   // slot holding tile it
    for (int it = 0; it < nIter; ++it) {
        if (it + 2 < nIter) {
            const int kb = (it + 2) << 5;
            short* sA = lA + sSt * 8192;
            short* sB = lB + sSt * 8192;
            async16(gA + kb,         sA);
            async16(gA + kb + rstep, sA + 512);
            async16(gB + kb,         sB);
            async16(gB + kb + rstep, sB + 512);
        }
        const int cb = sRd * 8192;
        bf16x8 af[4], bfr[4];
        #pragma unroll
        for (int i = 0; i < 4; ++i) af[i]  = *(const bf16x8*)(paBase + cb + i * 512);
        #pragma unroll
        for (int j = 0; j < 4; ++j) bfr[j] = *(const bf16x8*)(pbBase + cb + j * 512);
        #pragma unroll
        for (int i = 0; i < 4; ++i)
            #pragma unroll
            for (int j = 0; j < 4; ++j)
                acc[i][j] = __builtin_amdgcn_mfma_f32_16x16x32_bf16(
                                af[i], bfr[j], acc[i][j], 0, 0, 0);
        // tile it+1 must be visible after the barrier; keep it+2 in flight
        if (it + 2 < nIter)      asm volatile("s_waitcnt vmcnt(4)" ::: "memory");
        else if (it + 1 < nIter) asm volatile("s_waitcnt vmcnt(0)" ::: "memory");
        if (it + 1 < nIter) __builtin_amdgcn_s_barrier();
        sSt = (sSt == 2) ? 0 : sSt + 1;
        sRd = (sRd == 2) ? 0 : sRd + 1;
    }

    // ---- LDS-bounce epilogue (coalesced global I/O, rolling prefetch) ----
    // C/D layout: row = (wave&1)*64 + i*16 + quad*4 + reg; col = (wave>>1)*64 + j*16 + m16
    const int lrow = tid >> 3;        // 0..31
    const int seg  = tid & 7;         // 16-col segment
    const bool useCp = (cfB != 0.f);
    float lsum = 0.f;

    auto gofs = [&](int t) -> size_t {
        return (size_t)(rowBase + t * 32 + lrow) * Nn + colBase + seg * 16;
    };

    // prefetch registers (chunk 0 issued now; t+1 issued before chunk-t stores)
    u16x8 cc0{}, cc1{}, cp0{}, cp1{}, xq0{}, xq1{};
    float xfv[16];
    if constexpr (EPI == 1 || EPI == 2) {
        const size_t g = gofs(0);
        cc0 = *(const u16x8*)(Cc + g); cc1 = *(const u16x8*)(Cc + g + 8);
        if (useCp) { cp0 = *(const u16x8*)(Cpre + g); cp1 = *(const u16x8*)(Cpre + g + 8); }
    } else if constexpr (EPI == 3) {
        const size_t g = gofs(0);
        xq0 = *(const u16x8*)(Xb + g); xq1 = *(const u16x8*)(Xb + g + 8);
    } else if constexpr (EPI == 4) {
        const size_t g = gofs(0);
        #pragma unroll
        for (int q = 0; q < 4; ++q)
            *(f32x4*)&xfv[q * 4] = *(const f32x4*)(Xf + g + q * 4);
    }

    #pragma unroll
    for (int t = 0; t < 4; ++t) {
        __syncthreads();              // LDS free (K-loop or prev chunk done)
        if ((wave & 1) == (t >> 1)) {
            #pragma unroll
            for (int ii = 0; ii < 2; ++ii) {
                const int i   = (t & 1) * 2 + ii;
                const int lr0 = ii * 16 + quad * 4;
                #pragma unroll
                for (int r = 0; r < 4; ++r)
                    #pragma unroll
                    for (int j = 0; j < 4; ++j)
                        L[lr0 + r][(wave >> 1) * 64 + j * 16 + m16] = acc[i][j][r];
            }
        }
        __syncthreads();

        float v[16];
        #pragma unroll
        for (int q = 0; q < 4; ++q)
            *(f32x4*)&v[q * 4] = *(const f32x4*)&L[lrow][seg * 16 + q * 4];

        const size_t gidx = gofs(t);

        // issue next chunk's epilogue loads before this chunk's compute/stores
        u16x8 ncc0{}, ncc1{}, ncp0{}, ncp1{}, nxq0{}, nxq1{};
        float nxfv[16];
        if (t < 3) {
            const size_t gn = gofs(t + 1);
            if constexpr (EPI == 1 || EPI == 2) {
                ncc0 = *(const u16x8*)(Cc + gn); ncc1 = *(const u16x8*)(Cc + gn + 8);
                if (useCp) { ncp0 = *(const u16x8*)(Cpre + gn); ncp1 = *(const u16x8*)(Cpre + gn + 8); }
            } else if constexpr (EPI == 3) {
                nxq0 = *(const u16x8*)(Xb + gn); nxq1 = *(const u16x8*)(Xb + gn + 8);
            } else if constexpr (EPI == 4) {
                #pragma unroll
                for (int q = 0; q < 4; ++q)
                    *(f32x4*)&nxfv[q * 4] = *(const f32x4*)(Xf + gn + q * 4);
            }
        }

        if constexpr (EPI == 0) {
            u16x8 o0, o1;
            #pragma unroll
            for (int k = 0; k < 8; ++k) {
                o0[k] = f2bf(fmaxf(S_STEP * v[k]     - LAM, 0.f));
                o1[k] = f2bf(fmaxf(S_STEP * v[k + 8] - LAM, 0.f));
            }
            *(u16x8*)(OutB + gidx)     = o0;
            *(u16x8*)(OutB + gidx + 8) = o1;
        } else if constexpr (EPI == 1 || EPI == 2) {
            float w[16];
            #pragma unroll
            for (int k = 0; k < 8; ++k) {
                w[k]     = fmaxf(cfA * bf2f(cc0[k]) + cfB * bf2f(cp0[k])
                                 + S_STEP * v[k]     - LAM, 0.f);
                w[k + 8] = fmaxf(cfA * bf2f(cc1[k]) + cfB * bf2f(cp1[k])
                                 + S_STEP * v[k + 8] - LAM, 0.f);
            }
            u16x8 o0, o1;
            #pragma unroll
            for (int k = 0; k < 8; ++k) { o0[k] = f2bf(w[k]); o1[k] = f2bf(w[k + 8]); }
            *(u16x8*)(OutB + gidx)     = o0;
            *(u16x8*)(OutB + gidx + 8) = o1;
            if constexpr (EPI == 2) {
                #pragma unroll
                for (int q = 0; q < 4; ++q)
                    *(f32x4*)(Out32 + gidx + q * 4) = *(const f32x4*)&w[q * 4];
                #pragma unroll
                for (int k = 0; k < 16; ++k) lsum += w[k];   // w >= 0
            }
        } else if constexpr (EPI == 3) {
            u16x8 o0, o1;
            #pragma unroll
            for (int k = 0; k < 8; ++k) {
                o0[k] = f2bf(bf2f(xq0[k]) - v[k]);
                o1[k] = f2bf(bf2f(xq1[k]) - v[k + 8]);
            }
            *(u16x8*)(OutB + gidx)     = o0;
            *(u16x8*)(OutB + gidx + 8) = o1;
        } else {  // EPI 4: xp fp32 + r fp32 + rloss (fused finalize)
            float rv[16];
            #pragma unroll
            for (int k = 0; k < 16; ++k) {
                rv[k] = xfv[k] - v[k];
                lsum += rv[k] * rv[k];
            }
            #pragma unroll
            for (int q = 0; q < 4; ++q) {
                *(f32x4*)(Out32 + gidx + q * 4) = *(const f32x4*)&v[q * 4];
                *(f32x4*)(R32   + gidx + q * 4) = *(const f32x4*)&rv[q * 4];
            }
        }

        // rotate prefetch registers
        if (t < 3) {
            if constexpr (EPI == 1 || EPI == 2) {
                cc0 = ncc0; cc1 = ncc1;
                if (useCp) { cp0 = ncp0; cp1 = ncp1; }
            } else if constexpr (EPI == 3) {
                xq0 = nxq0; xq1 = nxq1;
            } else if constexpr (EPI == 4) {
                #pragma unroll
                for (int k = 0; k < 16; ++k) xfv[k] = nxfv[k];
            }
        }
    }

    if constexpr (EPI == 2 || EPI == 4) {
        #pragma unroll
        for (int off = 32; off; off >>= 1) lsum += __shfl_down(lsum, off, 64);
        if (lane == 0) red2[wave] = lsum;
        __syncthreads();
        if (tid == 0) {
            const float s = red2[0] + red2[1] + red2[2] + red2[3];
            atomicAdd(loss, (EPI == 2) ? 0.1f * s : s);
        }
    }
}

// ---------------------------------------------------------------------------
// prep: W [2048,512] fp32 -> Wb bf16 (same layout) + Wtb bf16 [512,2048]
// ---------------------------------------------------------------------------
__global__ __launch_bounds__(256)
void cvt_w_k(const float* __restrict__ W,
             unsigned short* __restrict__ Wb, unsigned short* __restrict__ Wtb)
{
    __shared__ unsigned short T[64][65];
    const int dBase = blockIdx.y * 64;
    const int cBase = blockIdx.x * 64;
    const int lc = threadIdx.x & 63;
    const int lr = threadIdx.x >> 6;
    #pragma unroll
    for (int p = 0; p < 16; ++p) {
        const int dl = p * 4 + lr;
        const size_t idx = (size_t)(dBase + dl) * 512 + cBase + lc;
        const unsigned short b = f2bf(W[idx]);
        Wb[idx] = b;
        T[dl][lc] = b;
    }
    __syncthreads();
    #pragma unroll
    for (int p = 0; p < 16; ++p) {
        const int cl = p * 4 + lr;
        Wtb[(size_t)(cBase + cl) * 2048 + dBase + lc] = T[lc][cl];
    }
}

__global__ __launch_bounds__(256)
void cvt_x_k(const float4* __restrict__ x4, ushort4* __restrict__ xb4, int n4)
{
    for (int i = blockIdx.x * 256 + threadIdx.x; i < n4; i += gridDim.x * 256) {
        const float4 v = x4[i];
        xb4[i] = make_ushort4(f2bf(v.x), f2bf(v.y), f2bf(v.z), f2bf(v.w));
    }
}

// 2MB Wtb -> cb1 copy (cb1 dead after step-4 EPI2)
__global__ __launch_bounds__(256)
void copy_wtb_k(const u16x8* __restrict__ src, u16x8* __restrict__ dst)
{
    const int i = blockIdx.x * 256 + threadIdx.x;
    dst[i] = src[i];
}

// ---------------------------------------------------------------------------
extern "C" void kernel_launch(void* const* d_in, const int* in_sizes, int n_in,
                              void* d_out, int out_size, void* d_ws, size_t ws_size,
                              hipStream_t stream)
{
    (void)in_sizes; (void)n_in; (void)out_size; (void)ws_size;

    constexpr int N = 16384, C = 512, D = 2048;
    constexpr size_t ND = (size_t)N * D;
    constexpr size_t NC = (size_t)N * C;

    const float* x = (const float*)d_in[0];   // [N, C]
    const float* W = (const float*)d_in[1];   // [D, C]

    float* out    = (float*)d_out;
    float* c_out  = out;                      // c  [N, D] fp32
    float* xp_out = out + ND;                 // xp [N, C] fp32
    float* r_out  = out + ND + NC;            // r  [N, C] fp32
    float* rloss  = out + ND + 2 * NC;
    float* closs  = rloss + 1;

    // ws: two bf16 c generations (64 MiB each)
    short* cb0 = (short*)d_ws;
    short* cb1 = cb0 + ND;

    // scratch in dead phases of d_out:
    // xp region: rb (16MB) + Wb (2MB)  — dead before final xp write (EPI4)
    // r  region: Wtb (2MB) + xb (16MB) — dead before EPI4's r write
    //   (Wtb is copied to cb1 first; EPI4 reads the copy)
    unsigned short* rb  = (unsigned short*)xp_out;            // [N,C] bf16
    unsigned short* Wb  = (unsigned short*)xp_out + NC;       // [D,C] bf16
    unsigned short* Wtb = (unsigned short*)r_out;             // [C,D] bf16
    unsigned short* xb  = (unsigned short*)r_out + (size_t)D * C;  // [N,C] bf16

    hipMemsetAsync((void*)rloss, 0, 2 * sizeof(float), stream);

    double tp = (std::sqrt(5.0) + 1.0) / 2.0;
    float cfA[5] = {0.f, 1.f, 0.f, 0.f, 0.f};
    float cfB[5] = {0.f, 0.f, 0.f, 0.f, 0.f};
    for (int i = 2; i < 5; ++i) {
        double t = (std::sqrt(1.0 + 4.0 * tp * tp) + 1.0) / 2.0;
        cfA[i] = (float)((tp + t - 1.0) / t);
        cfB[i] = (float)((1.0 - tp) / t);
        tp = t;
    }

    const dim3 blk(256);
    cvt_w_k<<<dim3(C / 64, D / 64), blk, 0, stream>>>(W, Wb, Wtb);
    cvt_x_k<<<dim3(1024), blk, 0, stream>>>((const float4*)x, (ushort4*)xb,
                                            (int)(NC / 4));

    // flat grids, T1 swizzle inside kernel
    const dim3 gridD((D / 128) * (N / 128));   // 2048 blocks, lbx=4
    const dim3 gridC((C / 128) * (N / 128));   //  512 blocks, lbx=2
    constexpr int LBX_D = 4, LBX_C = 2;

    // c0 = relu(S*(x@W^T) - LAM)
    gemm_bt<0><<<gridD, blk, 0, stream>>>((const short*)xb, (const short*)Wb,
                                          C, D, LBX_D, nullptr, nullptr,
                                          nullptr, nullptr,
                                          (unsigned short*)cb0, nullptr, nullptr,
                                          0.f, 0.f, nullptr);

    short* bufs[2] = {cb0, cb1};
    for (int i = 1; i < 5; ++i) {
        const short* cprev = bufs[(i - 1) & 1];   // c_{i-1}
        short*       cnew  = bufs[i & 1];         // c_{i-2} -> c_i (in place)
        const unsigned short* cpre2 =
            (i == 1) ? (const unsigned short*)cprev : (const unsigned short*)cnew;
        // r_{i-1} = x - c_{i-1} @ W   (bf16, via Wt; reads xb)
        gemm_bt<3><<<gridC, blk, 0, stream>>>(cprev, (const short*)Wtb,
                                              D, C, LBX_C, nullptr, nullptr,
                                              xb, nullptr,
                                              rb, nullptr, nullptr,
                                              0.f, 0.f, nullptr);
        // c_i = relu(cfA*c_{i-1} + cfB*c_{i-2} + S*(r@W^T) - LAM)
        if (i < 4)
            gemm_bt<1><<<gridD, blk, 0, stream>>>((const short*)rb, (const short*)Wb,
                                                  C, D, LBX_D,
                                                  (const unsigned short*)cprev,
                                                  cpre2, nullptr, nullptr,
                                                  (unsigned short*)cnew, nullptr,
                                                  nullptr, cfA[i], cfB[i], nullptr);
        else
            gemm_bt<2><<<gridD, blk, 0, stream>>>((const short*)rb, (const short*)Wb,
                                                  C, D, LBX_D,
                                                  (const unsigned short*)cprev,
                                                  cpre2, nullptr, nullptr,
                                                  (unsigned short*)cnew, c_out,
                                                  nullptr, cfA[i], cfB[i], closs);
    }

    // Wtb -> cb1 (cb1 dead after step-4 EPI2); EPI4 writes r over original Wtb
    copy_wtb_k<<<dim3(512), blk, 0, stream>>>((const u16x8*)Wtb, (u16x8*)cb1);

    // xp = c4 @ W (fp32), r = x - xp, rloss  — fused (overwrites rb/Wb/Wtb/xb)
    gemm_bt<4><<<gridC, blk, 0, stream>>>(cb0, (const short*)cb1,
                                          D, C, LBX_C, nullptr, nullptr,
                                          nullptr, x,
                                          nullptr, xp_out, r_out,
                                          0.f, 0.f, rloss);
}